// Round 1
// baseline (90.196 us; speedup 1.0000x reference)
//
#include <hip/hip_runtime.h>
#include <math.h>

#define B 64
#define T 1024
#define RNN_DIM 1024
#define EMB_DIM 512
#define ATTN_DIM 128
#define N_FILT 32
#define KSIZE 31
#define N_MEAN 8

#define LOGVAR_MIN (-4.605170185988091f)  /* log(0.1^2)   */
#define LOGVAR_MAX (7.2093654f)           /* log(36.77^2) */

// ---------------------------------------------------------------------------
// Kernel 1: processed_query[b,d] = sum_r hidden[b,r] * Wq[d,r]
// grid (32, B), block 256 (4 waves); each wave computes one d via split-K +
// shuffle reduction. Coalesced 256B/wave loads of both operands.
// ---------------------------------------------------------------------------
__global__ void pq_kernel(const float* __restrict__ hidden,
                          const float* __restrict__ Wq,
                          float* __restrict__ pq) {
    int b = blockIdx.y;
    int lane = threadIdx.x & 63;
    int wave = threadIdx.x >> 6;
    int d = blockIdx.x * 4 + wave;
    const float* h = hidden + (size_t)b * RNN_DIM;
    const float* w = Wq + (size_t)d * RNN_DIM;
    float acc = 0.f;
#pragma unroll
    for (int i = 0; i < RNN_DIM / 64; ++i) {
        int r = lane + i * 64;
        acc += h[r] * w[r];
    }
#pragma unroll
    for (int off = 32; off > 0; off >>= 1)
        acc += __shfl_down(acc, off, 64);
    if (lane == 0) pq[b * ATTN_DIM + d] = acc;
}

// ---------------------------------------------------------------------------
// Kernel 2: fused conv1d + location projection + tanh + mean-over-t partial.
// grid (8, B): each block owns a 128-wide t-tile of batch b.
//   phase 1: stage aw_cat window + conv_w into LDS
//   phase 2: loc[f][tt] tile into LDS (zero-padded conv)
//   phase 3: thread = (d, t-half); acc += tanh(pq[d] + loc�W_loc[d,:] + pm)
//   atomicAdd per-(b,d) partial sums (8 adds per address total).
// ---------------------------------------------------------------------------
#define TTILE 128
#define WIN 160  /* t0-16 .. t0+143 covers t+k-15 for t in tile, k in [0,31) */

__global__ void avg_kernel(const float* __restrict__ awcat,
                           const float* __restrict__ convw,
                           const float* __restrict__ Wloc,
                           const float* __restrict__ pq,
                           const float* __restrict__ pm,
                           float* __restrict__ avg_sum) {
    __shared__ float aw_s[2][WIN];
    __shared__ float conv_s[N_FILT][2][KSIZE];
    __shared__ float loc_s[N_FILT][TTILE];

    int b = blockIdx.y;
    int t0 = blockIdx.x * TTILE;
    int tid = threadIdx.x;

    for (int idx = tid; idx < 2 * WIN; idx += 256) {
        int c = idx / WIN, j = idx % WIN;
        int tg = t0 - 16 + j;
        aw_s[c][j] = (tg >= 0 && tg < T) ? awcat[(size_t)b * 2 * T + c * T + tg] : 0.f;
    }
    for (int idx = tid; idx < N_FILT * 2 * KSIZE; idx += 256)
        ((float*)conv_s)[idx] = convw[idx];
    __syncthreads();

    for (int idx = tid; idx < N_FILT * TTILE; idx += 256) {
        int f = idx >> 7, tt = idx & (TTILE - 1);
        float s = 0.f;
#pragma unroll
        for (int c = 0; c < 2; ++c)
#pragma unroll
            for (int k = 0; k < KSIZE; ++k)
                s += aw_s[c][tt + k + 1] * conv_s[f][c][k];
        loc_s[f][tt] = s;
    }
    __syncthreads();

    int d = tid & 127;
    int half = tid >> 7;
    float wl[N_FILT];
#pragma unroll
    for (int f = 0; f < N_FILT; ++f) wl[f] = Wloc[d * N_FILT + f];
    float pqv = pq[b * ATTN_DIM + d];

    float acc = 0.f;
    for (int tt = half; tt < TTILE; tt += 2) {
        float pmv = pm[((size_t)(b * T + t0 + tt)) * ATTN_DIM + d];
        float pl = 0.f;
#pragma unroll
        for (int f = 0; f < N_FILT; ++f) pl += loc_s[f][tt] * wl[f];
        float x = pqv + pl + pmv;
        // tanh(x) = 1 - 2/(exp(2x)+1)  (robust at +-inf, ~1e-6 abs err)
        float e = __expf(2.f * x);
        acc += 1.f - 2.f / (e + 1.f);
    }
    atomicAdd(&avg_sum[b * ATTN_DIM + d], acc);
}

// ---------------------------------------------------------------------------
// Kernel 3: per-batch scalar heads: softplus-sum mean increment, sigmoid
// logvar -> (means[b], stds[b]). 64 threads, one per batch; everything L2-hot.
// ---------------------------------------------------------------------------
__global__ void stats_kernel(const float* __restrict__ avg_sum,
                             const float* __restrict__ Wmean,
                             const float* __restrict__ Wlogvar,
                             const float* __restrict__ prev_means,
                             float* __restrict__ means,
                             float* __restrict__ stds) {
    int b = threadIdx.x;
    if (b >= B) return;
    float macc[N_MEAN];
#pragma unroll
    for (int m = 0; m < N_MEAN; ++m) macc[m] = 0.f;
    float lv = 0.f;
    for (int d = 0; d < ATTN_DIM; ++d) {
        float a = avg_sum[b * ATTN_DIM + d] * (1.f / (float)T);
#pragma unroll
        for (int m = 0; m < N_MEAN; ++m) macc[m] += a * Wmean[m * ATTN_DIM + d];
        lv += a * Wlogvar[d];
    }
    float mean_inc = 0.f;
#pragma unroll
    for (int m = 0; m < N_MEAN; ++m) {
        float x = macc[m];
        mean_inc += fmaxf(x, 0.f) + log1pf(expf(-fabsf(x)));  // softplus
    }
    means[b] = prev_means[b] + mean_inc;
    float sig = 1.f / (1.f + expf(-lv));
    float logvar = (LOGVAR_MAX - LOGVAR_MIN) * sig + LOGVAR_MIN;
    stds[b] = expf(0.5f * logvar);
}

// ---------------------------------------------------------------------------
// Kernel 4: weights + context. grid (16, B), block 256.
// Per 64-wide t-tile: compute p via erf-CDF difference, write weights, then
// early-exit if the whole tile is exactly zero (erff saturates in fp32, so
// p == 0.0f identically outside ~[mu-9sd, mu+9sd] -> skipping is exact).
// Otherwise float4-coalesced weighted accumulation of memory, LDS pair-
// combine, atomicAdd into zero-initialized context.
// ---------------------------------------------------------------------------
#define CTILE 64

__global__ void ctx_kernel(const float* __restrict__ memory,
                           const float* __restrict__ means,
                           const float* __restrict__ stds,
                           const unsigned char* __restrict__ mask,
                           float* __restrict__ out_ctx,
                           float* __restrict__ out_w) {
    __shared__ float w_s[CTILE];
    __shared__ float4 red_s[128];
    __shared__ int anyflag;

    int b = blockIdx.y;
    int t0 = blockIdx.x * CTILE;
    int tid = threadIdx.x;

    if (tid == 0) anyflag = 0;
    __syncthreads();

    float mu = means[b];
    float rsd = 1.f / stds[b];
    if (tid < CTILE) {
        int t = t0 + tid;
        const float inv_sqrt2 = 0.7071067811865476f;
        float z1 = ((float)t + 0.5f - mu) * rsd * inv_sqrt2;
        float z2 = ((float)t - 0.5f - mu) * rsd * inv_sqrt2;
        float p = 0.5f * (erff(z1) - erff(z2));
        if (mask[(size_t)b * T + t]) p = 0.f;
        w_s[tid] = p;
        out_w[(size_t)b * T + t] = p;
        if (p != 0.f) anyflag = 1;
    }
    __syncthreads();
    if (!anyflag) return;  // uniform: whole block exits together

    int e4 = tid & 127;   // float4 index over EMB=512
    int half = tid >> 7;
    const float4* mem4 = (const float4*)memory;
    float4 acc = make_float4(0.f, 0.f, 0.f, 0.f);
    for (int tt = half; tt < CTILE; tt += 2) {
        float wv = w_s[tt];
        float4 m = mem4[((size_t)(b * T + t0 + tt)) * (EMB_DIM / 4) + e4];
        acc.x += wv * m.x;
        acc.y += wv * m.y;
        acc.z += wv * m.z;
        acc.w += wv * m.w;
    }
    if (half == 1) red_s[e4] = acc;
    __syncthreads();
    if (half == 0) {
        float4 o = red_s[e4];
        acc.x += o.x; acc.y += o.y; acc.z += o.z; acc.w += o.w;
        float* dst = out_ctx + (size_t)b * EMB_DIM + e4 * 4;
        atomicAdd(dst + 0, acc.x);
        atomicAdd(dst + 1, acc.y);
        atomicAdd(dst + 2, acc.z);
        atomicAdd(dst + 3, acc.w);
    }
}

// ---------------------------------------------------------------------------
extern "C" void kernel_launch(void* const* d_in, const int* in_sizes, int n_in,
                              void* d_out, int out_size, void* d_ws, size_t ws_size,
                              hipStream_t stream) {
    const float* hidden  = (const float*)d_in[0];
    const float* memory  = (const float*)d_in[1];
    const float* pm      = (const float*)d_in[2];
    const float* awcat   = (const float*)d_in[3];
    const float* prevm   = (const float*)d_in[4];
    const unsigned char* mask = (const unsigned char*)d_in[5];
    const float* Wq      = (const float*)d_in[6];
    const float* convw   = (const float*)d_in[7];
    const float* Wloc    = (const float*)d_in[8];
    const float* Wmean   = (const float*)d_in[9];
    const float* Wlogvar = (const float*)d_in[10];

    float* ws      = (float*)d_ws;
    float* pq      = ws;            // 64*128
    float* avg_sum = ws + 8192;     // 64*128
    float* means   = ws + 16384;    // 64
    float* stds    = ws + 16448;    // 64

    float* out_ctx = (float*)d_out;               // (B, EMB)
    float* out_w   = out_ctx + B * EMB_DIM;       // (B, T)

    hipMemsetAsync(avg_sum, 0, 8192 * sizeof(float), stream);
    hipMemsetAsync(out_ctx, 0, (size_t)B * EMB_DIM * sizeof(float), stream);

    pq_kernel<<<dim3(32, B), 256, 0, stream>>>(hidden, Wq, pq);
    avg_kernel<<<dim3(8, B), 256, 0, stream>>>(awcat, convw, Wloc, pq, pm, avg_sum);
    stats_kernel<<<1, 64, 0, stream>>>(avg_sum, Wmean, Wlogvar, prevm, means, stds);
    ctx_kernel<<<dim3(16, B), 256, 0, stream>>>(memory, means, stds, mask, out_ctx, out_w);
}

// Round 2
// 72.361 us; speedup vs baseline: 1.2465x; 1.2465x over previous
//
#include <hip/hip_runtime.h>
#include <math.h>

#define B 64
#define T 1024
#define RNN_DIM 1024
#define EMB_DIM 512
#define ATTN_DIM 128
#define N_FILT 32
#define KSIZE 31
#define N_MEAN 8

#define LOGVAR_MIN (-4.605170185988091f)  /* log(0.1^2)   */
#define LOGVAR_MAX (7.2093654f)           /* log(36.77^2) */

// ---------------------------------------------------------------------------
// Kernel 1: processed_query[b,d] = sum_r hidden[b,r] * Wq[d,r]
// grid (32, B), block 256 (4 waves); each wave computes one d. float4 loads.
// ---------------------------------------------------------------------------
__global__ void pq_kernel(const float* __restrict__ hidden,
                          const float* __restrict__ Wq,
                          float* __restrict__ pq) {
    int b = blockIdx.y;
    int lane = threadIdx.x & 63;
    int wave = threadIdx.x >> 6;
    int d = blockIdx.x * 4 + wave;
    const float4* h = (const float4*)(hidden + (size_t)b * RNN_DIM);
    const float4* w = (const float4*)(Wq + (size_t)d * RNN_DIM);
    float acc = 0.f;
#pragma unroll
    for (int i = 0; i < RNN_DIM / 256; ++i) {
        int r = lane + i * 64;
        float4 hv = h[r], wv = w[r];
        acc += hv.x * wv.x + hv.y * wv.y + hv.z * wv.z + hv.w * wv.w;
    }
#pragma unroll
    for (int off = 32; off > 0; off >>= 1)
        acc += __shfl_down(acc, off, 64);
    if (lane == 0) pq[b * ATTN_DIM + d] = acc;
}

// ---------------------------------------------------------------------------
// Kernel 2: fused conv1d + loc projection + tanh + partial mean-over-t.
// grid (16, B), block 256, TTILE=64 t-rows per block.
//   phase L: stage aw window + conv weights -> LDS; compute loc[f][tt] tile
//   phase B: pl[tt][d] = pq[d] + sum_f loc[f][tt]*Wloc[d,f]   (LDS, 32 KB)
//   phase C: stream pm as float4 (lane=(row,e4)), acc += tanh(pl + pm)
//   phase R: cross-row LDS reduce, atomicAdd 128 scalars into avg_sum[b].
// LDS pool is phase-aliased: total 40 KB -> 4 blocks/CU (16 waves/CU).
// ---------------------------------------------------------------------------
#define TTILE 64
#define WIN2 94  /* t0-15 .. t0+63+15 */

__global__ __launch_bounds__(256, 4) void avg_kernel(
        const float* __restrict__ awcat,
        const float* __restrict__ convw,
        const float* __restrict__ Wloc,
        const float* __restrict__ pq,
        const float* __restrict__ pm,
        float* __restrict__ avg_sum) {
    __shared__ __align__(16) char pool[40960];
    float* pl_s   = (float*)pool;                    // [64][128] f32, 32 KB (phases B,C)
    float* aw_s   = (float*)pool;                    // [2][94]  (phase L only, aliases pl)
    float* conv_s = (float*)(pool + 768);            // [32][2][31] (phase L only)
    float* loc_s  = (float*)(pool + 32768);          // [32][64], 8 KB (phases L,B)
    float4* red_s = (float4*)(pool + 32768);         // [8][32] f4 (phase R, aliases loc)

    int b = blockIdx.y;
    int t0 = blockIdx.x * TTILE;
    int tid = threadIdx.x;

    // ---- phase L: stage ----
    for (int idx = tid; idx < 2 * WIN2; idx += 256) {
        int c = idx / WIN2, j = idx % WIN2;
        int tg = t0 - 15 + j;
        aw_s[c * WIN2 + j] =
            (tg >= 0 && tg < T) ? awcat[(size_t)b * 2 * T + c * T + tg] : 0.f;
    }
    for (int idx = tid; idx < N_FILT * 2 * KSIZE; idx += 256)
        conv_s[idx] = convw[idx];
    __syncthreads();

    // ---- conv: loc[f][tt] ----
    for (int idx = tid; idx < N_FILT * TTILE; idx += 256) {
        int f = idx >> 6, tt = idx & (TTILE - 1);
        float s = 0.f;
#pragma unroll
        for (int c = 0; c < 2; ++c)
#pragma unroll
            for (int k = 0; k < KSIZE; ++k)
                s += aw_s[c * WIN2 + tt + k] * conv_s[(f * 2 + c) * KSIZE + k];
        loc_s[f * TTILE + tt] = s;
    }
    __syncthreads();

    // ---- phase B: pl[tt][d] (overwrites aw/conv region; loc still live) ----
    {
        int d = tid & 127;
        int half = tid >> 7;
        float wl[N_FILT];
#pragma unroll
        for (int f = 0; f < N_FILT; ++f) wl[f] = Wloc[d * N_FILT + f];
        float pqv = pq[b * ATTN_DIM + d];
        for (int tt = half; tt < TTILE; tt += 2) {
            float s = pqv;
#pragma unroll
            for (int f = 0; f < N_FILT; ++f) s += loc_s[f * TTILE + tt] * wl[f];
            pl_s[tt * ATTN_DIM + d] = s;
        }
    }
    __syncthreads();

    // ---- phase C: stream pm, tanh, accumulate ----
    int e4 = tid & 31;        // float4 lane over 128 dims
    int row = tid >> 5;       // 0..7
    const float4* pmb = (const float4*)pm + ((size_t)(b * T + t0)) * (ATTN_DIM / 4);
    const float4* pl4 = (const float4*)pl_s;
    float4 acc = make_float4(0.f, 0.f, 0.f, 0.f);
#pragma unroll
    for (int tt = row; tt < TTILE; tt += 8) {
        float4 m = pmb[tt * 32 + e4];
        float4 p = pl4[tt * 32 + e4];
        float ex, x;
        x = p.x + m.x; ex = __expf(2.f * x); acc.x += 1.f - 2.f / (ex + 1.f);
        x = p.y + m.y; ex = __expf(2.f * x); acc.y += 1.f - 2.f / (ex + 1.f);
        x = p.z + m.z; ex = __expf(2.f * x); acc.z += 1.f - 2.f / (ex + 1.f);
        x = p.w + m.w; ex = __expf(2.f * x); acc.w += 1.f - 2.f / (ex + 1.f);
    }
    if (row != 0) red_s[row * 32 + e4] = acc;
    __syncthreads();
    if (row == 0) {
#pragma unroll
        for (int r = 1; r < 8; ++r) {
            float4 o = red_s[r * 32 + e4];
            acc.x += o.x; acc.y += o.y; acc.z += o.z; acc.w += o.w;
        }
        float* dst = avg_sum + b * ATTN_DIM + e4 * 4;
        atomicAdd(dst + 0, acc.x);
        atomicAdd(dst + 1, acc.y);
        atomicAdd(dst + 2, acc.z);
        atomicAdd(dst + 3, acc.w);
    }
}

// ---------------------------------------------------------------------------
// Kernel 3: per-batch heads. grid B blocks x 64 lanes; butterfly reduce.
// ---------------------------------------------------------------------------
__global__ void stats_kernel(const float* __restrict__ avg_sum,
                             const float* __restrict__ Wmean,
                             const float* __restrict__ Wlogvar,
                             const float* __restrict__ prev_means,
                             float* __restrict__ means,
                             float* __restrict__ stds) {
    int b = blockIdx.x;
    int lane = threadIdx.x;
    float macc[N_MEAN];
#pragma unroll
    for (int m = 0; m < N_MEAN; ++m) macc[m] = 0.f;
    float lv = 0.f;
#pragma unroll
    for (int i = 0; i < 2; ++i) {
        int d = lane + i * 64;
        float a = avg_sum[b * ATTN_DIM + d] * (1.f / (float)T);
#pragma unroll
        for (int m = 0; m < N_MEAN; ++m) macc[m] += a * Wmean[m * ATTN_DIM + d];
        lv += a * Wlogvar[d];
    }
#pragma unroll
    for (int off = 32; off > 0; off >>= 1) {
#pragma unroll
        for (int m = 0; m < N_MEAN; ++m) macc[m] += __shfl_xor(macc[m], off, 64);
        lv += __shfl_xor(lv, off, 64);
    }
    if (lane == 0) {
        float mean_inc = 0.f;
#pragma unroll
        for (int m = 0; m < N_MEAN; ++m) {
            float x = macc[m];
            mean_inc += fmaxf(x, 0.f) + log1pf(expf(-fabsf(x)));  // softplus
        }
        means[b] = prev_means[b] + mean_inc;
        float sig = 1.f / (1.f + expf(-lv));
        float logvar = (LOGVAR_MAX - LOGVAR_MIN) * sig + LOGVAR_MIN;
        stds[b] = expf(0.5f * logvar);
    }
}

// ---------------------------------------------------------------------------
// Kernel 4: weights + context. grid (16, B), block 256.
// p == 0.0f exactly outside ~[mu-9sd, mu+9sd] (erff saturates in fp32) ->
// tile-level early exit is exact. Non-zero tiles do float4 weighted sums.
// ---------------------------------------------------------------------------
#define CTILE 64

__global__ void ctx_kernel(const float* __restrict__ memory,
                           const float* __restrict__ means,
                           const float* __restrict__ stds,
                           const unsigned char* __restrict__ mask,
                           float* __restrict__ out_ctx,
                           float* __restrict__ out_w) {
    __shared__ float w_s[CTILE];
    __shared__ float4 red_s[128];
    __shared__ int anyflag;

    int b = blockIdx.y;
    int t0 = blockIdx.x * CTILE;
    int tid = threadIdx.x;

    if (tid == 0) anyflag = 0;
    __syncthreads();

    float mu = means[b];
    float rsd = 1.f / stds[b];
    if (tid < CTILE) {
        int t = t0 + tid;
        const float inv_sqrt2 = 0.7071067811865476f;
        float z1 = ((float)t + 0.5f - mu) * rsd * inv_sqrt2;
        float z2 = ((float)t - 0.5f - mu) * rsd * inv_sqrt2;
        float p = 0.5f * (erff(z1) - erff(z2));
        if (mask[(size_t)b * T + t]) p = 0.f;
        w_s[tid] = p;
        out_w[(size_t)b * T + t] = p;
        if (p != 0.f) anyflag = 1;
    }
    __syncthreads();
    if (!anyflag) return;  // uniform exit

    int e4 = tid & 127;
    int half = tid >> 7;
    const float4* mem4 = (const float4*)memory;
    float4 acc = make_float4(0.f, 0.f, 0.f, 0.f);
    for (int tt = half; tt < CTILE; tt += 2) {
        float wv = w_s[tt];
        float4 m = mem4[((size_t)(b * T + t0 + tt)) * (EMB_DIM / 4) + e4];
        acc.x += wv * m.x;
        acc.y += wv * m.y;
        acc.z += wv * m.z;
        acc.w += wv * m.w;
    }
    if (half == 1) red_s[e4] = acc;
    __syncthreads();
    if (half == 0) {
        float4 o = red_s[e4];
        acc.x += o.x; acc.y += o.y; acc.z += o.z; acc.w += o.w;
        float* dst = out_ctx + (size_t)b * EMB_DIM + e4 * 4;
        atomicAdd(dst + 0, acc.x);
        atomicAdd(dst + 1, acc.y);
        atomicAdd(dst + 2, acc.z);
        atomicAdd(dst + 3, acc.w);
    }
}

// ---------------------------------------------------------------------------
extern "C" void kernel_launch(void* const* d_in, const int* in_sizes, int n_in,
                              void* d_out, int out_size, void* d_ws, size_t ws_size,
                              hipStream_t stream) {
    const float* hidden  = (const float*)d_in[0];
    const float* memory  = (const float*)d_in[1];
    const float* pm      = (const float*)d_in[2];
    const float* awcat   = (const float*)d_in[3];
    const float* prevm   = (const float*)d_in[4];
    const unsigned char* mask = (const unsigned char*)d_in[5];
    const float* Wq      = (const float*)d_in[6];
    const float* convw   = (const float*)d_in[7];
    const float* Wloc    = (const float*)d_in[8];
    const float* Wmean   = (const float*)d_in[9];
    const float* Wlogvar = (const float*)d_in[10];

    float* ws      = (float*)d_ws;
    float* pq      = ws;            // 64*128
    float* avg_sum = ws + 8192;     // 64*128
    float* means   = ws + 16384;    // 64
    float* stds    = ws + 16448;    // 64

    float* out_ctx = (float*)d_out;               // (B, EMB)
    float* out_w   = out_ctx + B * EMB_DIM;       // (B, T)

    hipMemsetAsync(avg_sum, 0, 8192 * sizeof(float), stream);
    hipMemsetAsync(out_ctx, 0, (size_t)B * EMB_DIM * sizeof(float), stream);

    pq_kernel<<<dim3(32, B), 256, 0, stream>>>(hidden, Wq, pq);
    avg_kernel<<<dim3(16, B), 256, 0, stream>>>(awcat, convw, Wloc, pq, pm, avg_sum);
    stats_kernel<<<B, 64, 0, stream>>>(avg_sum, Wmean, Wlogvar, prevm, means, stds);
    ctx_kernel<<<dim3(16, B), 256, 0, stream>>>(memory, means, stds, mask, out_ctx, out_w);
}

// Round 3
// 49.453 us; speedup vs baseline: 1.8239x; 1.4632x over previous
//
#include <hip/hip_runtime.h>
#include <math.h>

#define B 64
#define T 1024
#define RNN_DIM 1024
#define EMB_DIM 512
#define ATTN_DIM 128
#define N_FILT 32
#define KSIZE 31
#define N_MEAN 8

#define LOGVAR_MIN (-4.605170185988091f)  /* log(0.1^2)   */
#define LOGVAR_MAX (7.2093654f)           /* log(36.77^2) */

// ---------------------------------------------------------------------------
// Kernel 1: processed_query[b,d] = sum_r hidden[b,r] * Wq[d,r]
// grid (32, B), block 256 (4 waves); one wave per d. float4 loads.
// ---------------------------------------------------------------------------
__global__ void pq_kernel(const float* __restrict__ hidden,
                          const float* __restrict__ Wq,
                          float* __restrict__ pq) {
    int b = blockIdx.y;
    int lane = threadIdx.x & 63;
    int wave = threadIdx.x >> 6;
    int d = blockIdx.x * 4 + wave;
    const float4* h = (const float4*)(hidden + (size_t)b * RNN_DIM);
    const float4* w = (const float4*)(Wq + (size_t)d * RNN_DIM);
    float acc = 0.f;
#pragma unroll
    for (int i = 0; i < RNN_DIM / 256; ++i) {
        int r = lane + i * 64;
        float4 hv = h[r], wv = w[r];
        acc += hv.x * wv.x + hv.y * wv.y + hv.z * wv.z + hv.w * wv.w;
    }
#pragma unroll
    for (int off = 32; off > 0; off >>= 1)
        acc += __shfl_down(acc, off, 64);
    if (lane == 0) pq[b * ATTN_DIM + d] = acc;
}

// ---------------------------------------------------------------------------
// Kernel 2: fused conv1d + loc projection + tanh + partial mean-over-t.
// grid (16, B), block 256, TTILE=64.
//  conv phase: thread=(f=tid&31, tg=tid>>5). conv weights (62) + aw window
//    (2x40, reg-aligned since tg*8-16 is 16B aligned) live in REGISTERS;
//    only 20 ds_read_b128 per thread. Writes loc[tt][f] (2-way bank = free).
//  BC phase: thread=(e4=tid&31 -> d-quad, g=tid>>5 -> 8 tt rows).
//    Wloc rows for 4 d in 128 regs (L2-hot global). Per tt: 8 broadcast
//    ds_read_b128 of loc row + 128 FMA + coalesced float4 pm load + tanh.
//  Non-atomic per-tile partial to ws (stats sums 16 tiles). No memset.
// ---------------------------------------------------------------------------
__global__ __launch_bounds__(256, 2) void avg_kernel(
        const float* __restrict__ awcat,
        const float* __restrict__ convw,
        const float* __restrict__ Wloc,
        const float* __restrict__ pq,
        const float* __restrict__ pm,
        float* __restrict__ avg_part) {
    __shared__ __align__(16) float aw_s[2][96];
    __shared__ __align__(16) float loc_s[64][32];
    __shared__ __align__(16) float4 red_s[8][32];

    int b = blockIdx.y;
    int t0 = blockIdx.x * 64;
    int tid = threadIdx.x;

    // ---- stage aw window [t0-16, t0+80) ----
    if (tid < 192) {
        int c = tid / 96, j = tid % 96;
        int tg = t0 - 16 + j;
        aw_s[c][j] = (tg >= 0 && tg < T) ? awcat[(size_t)b * 2 * T + c * T + tg] : 0.f;
    }

    int f = tid & 31;   // filter
    int tg = tid >> 5;  // tt octet
    // conv weights -> regs (global, L1/L2-hot: 8 KB total)
    float wv0[KSIZE], wv1[KSIZE];
#pragma unroll
    for (int k = 0; k < KSIZE; ++k) {
        wv0[k] = convw[f * 2 * KSIZE + k];
        wv1[k] = convw[f * 2 * KSIZE + KSIZE + k];
    }
    __syncthreads();

    // aw window -> regs: aligned span [tg*8, tg*8+40) in aw_s
    float a0[40], a1[40];
#pragma unroll
    for (int j = 0; j < 10; ++j) {
        float4 v0 = *(const float4*)&aw_s[0][tg * 8 + 4 * j];
        float4 v1 = *(const float4*)&aw_s[1][tg * 8 + 4 * j];
        a0[4 * j] = v0.x; a0[4 * j + 1] = v0.y; a0[4 * j + 2] = v0.z; a0[4 * j + 3] = v0.w;
        a1[4 * j] = v1.x; a1[4 * j + 1] = v1.y; a1[4 * j + 2] = v1.z; a1[4 * j + 3] = v1.w;
    }

    // conv: loc[tt][f], tt = tg*8+i ; aw(t0+tt+k-15) = reg[i+k+1]
#pragma unroll
    for (int i = 0; i < 8; ++i) {
        float s = 0.f;
#pragma unroll
        for (int k = 0; k < KSIZE; ++k)
            s += a0[i + k + 1] * wv0[k] + a1[i + k + 1] * wv1[k];
        loc_s[tg * 8 + i][f] = s;
    }
    __syncthreads();

    // ---- BC phase ----
    int e4 = tid & 31;  // d-quad index
    int g = tid >> 5;   // tt octet
    float wl0[32], wl1[32], wl2[32], wl3[32];
    {
        const float4* wl4 = (const float4*)Wloc;
#pragma unroll
        for (int j = 0; j < 8; ++j) {
            float4 v;
            v = wl4[(e4 * 4 + 0) * 8 + j];
            wl0[4 * j] = v.x; wl0[4 * j + 1] = v.y; wl0[4 * j + 2] = v.z; wl0[4 * j + 3] = v.w;
            v = wl4[(e4 * 4 + 1) * 8 + j];
            wl1[4 * j] = v.x; wl1[4 * j + 1] = v.y; wl1[4 * j + 2] = v.z; wl1[4 * j + 3] = v.w;
            v = wl4[(e4 * 4 + 2) * 8 + j];
            wl2[4 * j] = v.x; wl2[4 * j + 1] = v.y; wl2[4 * j + 2] = v.z; wl2[4 * j + 3] = v.w;
            v = wl4[(e4 * 4 + 3) * 8 + j];
            wl3[4 * j] = v.x; wl3[4 * j + 1] = v.y; wl3[4 * j + 2] = v.z; wl3[4 * j + 3] = v.w;
        }
    }
    float4 pqv = ((const float4*)pq)[b * 32 + e4];
    const float4* pmb = (const float4*)pm + (size_t)(b * T + t0) * 32;
    float4 acc = make_float4(0.f, 0.f, 0.f, 0.f);

#pragma unroll
    for (int i = 0; i < 8; ++i) {
        int tt = g * 8 + i;
        float lr[32];
#pragma unroll
        for (int j = 0; j < 8; ++j) {
            float4 v = *(const float4*)&loc_s[tt][4 * j];
            lr[4 * j] = v.x; lr[4 * j + 1] = v.y; lr[4 * j + 2] = v.z; lr[4 * j + 3] = v.w;
        }
        float4 pmv = pmb[tt * 32 + e4];
        float x0 = pqv.x + pmv.x;
        float x1 = pqv.y + pmv.y;
        float x2 = pqv.z + pmv.z;
        float x3 = pqv.w + pmv.w;
#pragma unroll
        for (int ff = 0; ff < 32; ++ff) {
            x0 += lr[ff] * wl0[ff];
            x1 += lr[ff] * wl1[ff];
            x2 += lr[ff] * wl2[ff];
            x3 += lr[ff] * wl3[ff];
        }
        float e;
        e = __expf(2.f * x0); acc.x += 1.f - 2.f / (e + 1.f);
        e = __expf(2.f * x1); acc.y += 1.f - 2.f / (e + 1.f);
        e = __expf(2.f * x2); acc.z += 1.f - 2.f / (e + 1.f);
        e = __expf(2.f * x3); acc.w += 1.f - 2.f / (e + 1.f);
    }

    red_s[g][e4] = acc;
    __syncthreads();
    if (g == 0) {
#pragma unroll
        for (int r = 1; r < 8; ++r) {
            float4 o = red_s[r][e4];
            acc.x += o.x; acc.y += o.y; acc.z += o.z; acc.w += o.w;
        }
        float4* dst = (float4*)(avg_part + ((size_t)(b * 16 + blockIdx.x)) * ATTN_DIM) + e4;
        *dst = acc;
    }
}

// ---------------------------------------------------------------------------
// Kernel 3: sum 16 tile-partials -> avg; heads -> means/stds. grid B x 64.
// ---------------------------------------------------------------------------
__global__ void stats_kernel(const float* __restrict__ avg_part,
                             const float* __restrict__ Wmean,
                             const float* __restrict__ Wlogvar,
                             const float* __restrict__ prev_means,
                             float* __restrict__ means,
                             float* __restrict__ stds) {
    int b = blockIdx.x;
    int lane = threadIdx.x;
    float macc[N_MEAN];
#pragma unroll
    for (int m = 0; m < N_MEAN; ++m) macc[m] = 0.f;
    float lv = 0.f;
#pragma unroll
    for (int i = 0; i < 2; ++i) {
        int d = lane + i * 64;
        float s = 0.f;
#pragma unroll
        for (int t = 0; t < 16; ++t)
            s += avg_part[((size_t)(b * 16 + t)) * ATTN_DIM + d];
        float a = s * (1.f / (float)T);
#pragma unroll
        for (int m = 0; m < N_MEAN; ++m) macc[m] += a * Wmean[m * ATTN_DIM + d];
        lv += a * Wlogvar[d];
    }
#pragma unroll
    for (int off = 32; off > 0; off >>= 1) {
#pragma unroll
        for (int m = 0; m < N_MEAN; ++m) macc[m] += __shfl_xor(macc[m], off, 64);
        lv += __shfl_xor(lv, off, 64);
    }
    if (lane == 0) {
        float mean_inc = 0.f;
#pragma unroll
        for (int m = 0; m < N_MEAN; ++m) {
            float x = macc[m];
            mean_inc += fmaxf(x, 0.f) + log1pf(expf(-fabsf(x)));  // softplus
        }
        means[b] = prev_means[b] + mean_inc;
        float sig = 1.f / (1.f + expf(-lv));
        float logvar = (LOGVAR_MAX - LOGVAR_MIN) * sig + LOGVAR_MIN;
        stds[b] = expf(0.5f * logvar);
    }
}

// ---------------------------------------------------------------------------
// Kernel 4: weights + context. ONE block per batch (grid B, 256 threads).
// Computes all T weights (p==0.0f exactly outside ~9 sigma since erff
// saturates in fp32), finds nonzero support [lo,hi], streams only that
// range of memory, writes out_ctx[b] non-atomically (zeros if empty).
// ---------------------------------------------------------------------------
__global__ void ctx_kernel(const float* __restrict__ memory,
                           const float* __restrict__ means,
                           const float* __restrict__ stds,
                           const unsigned char* __restrict__ mask,
                           float* __restrict__ out_ctx,
                           float* __restrict__ out_w) {
    __shared__ float w_s[T];
    __shared__ float4 red_s[128];
    __shared__ int s_lo[4], s_hi[4];

    int b = blockIdx.x;
    int tid = threadIdx.x;
    float mu = means[b];
    float rsd = 1.f / stds[b];
    const float is2 = 0.7071067811865476f;

    int lo = T, hi = -1;
#pragma unroll
    for (int r = 0; r < 4; ++r) {
        int t = tid + r * 256;
        float z1 = ((float)t + 0.5f - mu) * rsd * is2;
        float z2 = ((float)t - 0.5f - mu) * rsd * is2;
        float p = 0.5f * (erff(z1) - erff(z2));
        if (mask[(size_t)b * T + t]) p = 0.f;
        w_s[t] = p;
        out_w[(size_t)b * T + t] = p;
        if (p != 0.f) { lo = min(lo, t); hi = max(hi, t); }
    }
#pragma unroll
    for (int off = 32; off > 0; off >>= 1) {
        lo = min(lo, __shfl_xor(lo, off, 64));
        hi = max(hi, __shfl_xor(hi, off, 64));
    }
    int lane = tid & 63, wv = tid >> 6;
    if (lane == 0) { s_lo[wv] = lo; s_hi[wv] = hi; }
    __syncthreads();
    lo = min(min(s_lo[0], s_lo[1]), min(s_lo[2], s_lo[3]));
    hi = max(max(s_hi[0], s_hi[1]), max(s_hi[2], s_hi[3]));

    int e4 = tid & 127;   // float4 over EMB=512
    int half = tid >> 7;
    const float4* m4 = (const float4*)memory + (size_t)b * T * (EMB_DIM / 4);
    float4 acc = make_float4(0.f, 0.f, 0.f, 0.f);
    for (int t = lo + half; t <= hi; t += 2) {
        float wvv = w_s[t];
        float4 mm = m4[(size_t)t * (EMB_DIM / 4) + e4];
        acc.x += wvv * mm.x;
        acc.y += wvv * mm.y;
        acc.z += wvv * mm.z;
        acc.w += wvv * mm.w;
    }
    if (half == 1) red_s[e4] = acc;
    __syncthreads();
    if (half == 0) {
        float4 o = red_s[e4];
        acc.x += o.x; acc.y += o.y; acc.z += o.z; acc.w += o.w;
        ((float4*)(out_ctx + (size_t)b * EMB_DIM))[e4] = acc;
    }
}

// ---------------------------------------------------------------------------
extern "C" void kernel_launch(void* const* d_in, const int* in_sizes, int n_in,
                              void* d_out, int out_size, void* d_ws, size_t ws_size,
                              hipStream_t stream) {
    const float* hidden  = (const float*)d_in[0];
    const float* memory  = (const float*)d_in[1];
    const float* pm      = (const float*)d_in[2];
    const float* awcat   = (const float*)d_in[3];
    const float* prevm   = (const float*)d_in[4];
    const unsigned char* mask = (const unsigned char*)d_in[5];
    const float* Wq      = (const float*)d_in[6];
    const float* convw   = (const float*)d_in[7];
    const float* Wloc    = (const float*)d_in[8];
    const float* Wmean   = (const float*)d_in[9];
    const float* Wlogvar = (const float*)d_in[10];

    float* ws       = (float*)d_ws;
    float* pq       = ws;                    // 64*128
    float* avg_part = ws + 8192;             // 64*16*128
    float* means    = ws + 8192 + 131072;    // 64
    float* stds     = means + 64;            // 64

    float* out_ctx = (float*)d_out;          // (B, EMB)
    float* out_w   = out_ctx + B * EMB_DIM;  // (B, T)

    pq_kernel<<<dim3(32, B), 256, 0, stream>>>(hidden, Wq, pq);
    avg_kernel<<<dim3(16, B), 256, 0, stream>>>(awcat, convw, Wloc, pq, pm, avg_part);
    stats_kernel<<<B, 64, 0, stream>>>(avg_part, Wmean, Wlogvar, prevm, means, stds);
    ctx_kernel<<<B, 256, 0, stream>>>(memory, means, stds, mask, out_ctx, out_w);
}